// Round 2
// baseline (880.743 us; speedup 1.0000x reference)
//
#include <hip/hip_runtime.h>

// WindowAttention (Swin-style) on gfx950 — R5.
// R5 changes vs R4:
//   * Both GEMMs rewritten: 256x256 tile, BK=32, 8 waves (2Mx4N), 4-slot LDS
//     ring (128 KiB), counted s_waitcnt vmcnt(8) (never drains in main loop),
//     prefetch 3 K-tiles ahead, one raw s_barrier per K-tile, setprio around
//     the MFMA cluster, chunk-swizzled LDS (pre-swizzled global source +
//     swizzled ds_read; linear global_load_lds dest).
//   * gemm_qkv epilogue: R4's LDS-staged coalesced writeout, adapted to 256^2
//     (two 128-row halves staged in [128][264] padded LDS).
//   * gemm_bt epilogue: direct coalesced f32 stores (unchanged scheme).
//   * attn2 / conv / build_combined / zero_vpad unchanged.
// ws layout (bytes): unchanged from R3/R4.

typedef unsigned short u16;
typedef __attribute__((ext_vector_type(8))) short short8;
typedef __attribute__((ext_vector_type(4))) float floatx4;

#define B_WIN 2048
#define SEQ 49
#define DIM 512
#define NHEAD 16
#define HD 32
#define MROWS (B_WIN * SEQ)          // 100352
#define QTOT 51380224u               // 2048*16*49*32 elems (one Q or K plane set)
#define VOFF 102760448u              // elem offset of Vt planes ( = 2*QTOT)

__device__ __forceinline__ u16 f2bf(float x) {
    unsigned u = __float_as_uint(x);
    u += 0x7fffu + ((u >> 16) & 1u);   // RNE
    return (u16)(u >> 16);
}

__device__ __forceinline__ void async_ld16(const void* g, void* l) {
    __builtin_amdgcn_global_load_lds(
        (const __attribute__((address_space(1))) void*)g,
        (__attribute__((address_space(3))) void*)l, 16, 0, 0);
}

// ---------- conversion kernels ----------
__global__ void conv_f32_bf16(const float* __restrict__ in, u16* __restrict__ out, int n4) {
    int id = blockIdx.x * 256 + threadIdx.x;
    if (id >= n4) return;
    float4 v = ((const float4*)in)[id];
    uint2 o;
    o.x = (unsigned)f2bf(v.x) | ((unsigned)f2bf(v.y) << 16);
    o.y = (unsigned)f2bf(v.z) | ((unsigned)f2bf(v.w) << 16);
    *(uint2*)(out + (size_t)id * 4) = o;
}

// in: [512][Cn] f32 (k-major). out: [Cn][512] bf16 (n-major).
__global__ void transpose_conv(const float* __restrict__ in, u16* __restrict__ out, int Cn) {
    int id = blockIdx.x * 256 + threadIdx.x;
    if (id >= Cn * 512) return;
    int k = id & 511;
    int n = id >> 9;
    out[id] = f2bf(in[(size_t)k * Cn + n]);
}

// combined[w][h][i][j] = bias_table[rel_idx[i*49+j]][h] + mask[w][i][j]
__global__ void build_combined(const float* __restrict__ mask, const float* __restrict__ bias_table,
                               const int* __restrict__ rel_idx, float* __restrict__ cmb) {
    int id = blockIdx.x * 256 + threadIdx.x;    // 64*16*2401 = 2,458,624
    if (id >= 64 * 16 * 2401) return;
    int ij = id % 2401;
    int wh = id / 2401;
    int h = wh & 15, w = wh >> 4;
    cmb[id] = bias_table[rel_idx[ij] * NHEAD + h] + mask[(size_t)w * 2401 + ij];
}

// zero V^T pad region: elems s in [48,64) per (bh, d). gemm_qkv later rewrites s=48.
__global__ void zero_vpad(u16* __restrict__ qkvp) {
    int id = blockIdx.x * 256 + threadIdx.x;     // 2048*16*32 = 1,048,576
    if (id >= 2048 * 16 * 32) return;
    uint4 z = {0u, 0u, 0u, 0u};
    u16* p = qkvp + VOFF + (size_t)id * 64 + 48; // byte offset 96: 16B aligned
    *(uint4*)p = z;                               // elems 48..55
    *((uint4*)p + 1) = z;                         // elems 56..63
}

// ---------- GEMM1: qkv = x @ qkv_w + b, scattered to per-head planes ----------
// 256x256 tile, BK=32, 8 waves (2Mx4N), 4-slot LDS ring, counted vmcnt pipeline.
__global__ __launch_bounds__(512, 2)
void gemm_qkv(const u16* __restrict__ A, const u16* __restrict__ Bt,
              const float* __restrict__ bias, u16* __restrict__ qkvp) {
    const int K = 512;
    const int tid  = threadIdx.x;
    const int lane = tid & 63, wave = tid >> 6;
    const int quad = lane >> 4, l16 = lane & 15;
    const int wr = wave >> 2, wc = wave & 3;      // 2 x 4 waves

    // XCD-bijective swizzle: 2352 blocks = 8 * 294.
    const int flat = blockIdx.y * 6 + blockIdx.x;
    const int swz  = (flat & 7) * 294 + (flat >> 3);
    const int bx = swz % 6;
    const int by = swz / 6;
    const int m0 = by * 256, n0 = bx * 256;

    // LDS: 4-slot ring, slot = 16384 u16 (A[256][32] @0, B[256][32] @8192).
    // Epilogue reuses smem[0..33791] as a [128][264] padded bf16 stage.
    __shared__ u16 smem[65536];                  // 128 KiB

    const u16* Ab = A  + (size_t)m0 * K;
    const u16* Bb = Bt + (size_t)n0 * K;

    // staging: 4 x global_load_lds(16B) per thread per K-tile.
    // chunk pre-swizzle: LDS chunk p of row holds global chunk p ^ ((row>>1)&3).
    const int st_row = tid >> 2;                               // 0..127
    const int st_chk = (((tid & 3) ^ ((tid >> 3) & 3))) * 8;   // swizzled src chunk
    auto stage = [&](int t) {
        const int slot = (t & 3) * 16384;
        const u16* as_ = Ab + (size_t)st_row * K + t * 32 + st_chk;
        const u16* bs_ = Bb + (size_t)st_row * K + t * 32 + st_chk;
        async_ld16(as_,                    &smem[slot + tid * 8]);
        async_ld16(as_ + (size_t)128 * K,  &smem[slot + 4096 + tid * 8]);
        async_ld16(bs_,                    &smem[slot + 8192 + tid * 8]);
        async_ld16(bs_ + (size_t)128 * K,  &smem[slot + 8192 + 4096 + tid * 8]);
    };

    floatx4 acc[8][4] = {};
    const int qx = (quad ^ ((l16 >> 1) & 3)) * 8;              // swizzled read chunk

    auto compute = [&](int t) {
        const int slot = (t & 3) * 16384;
        short8 a[8], b[4];
#pragma unroll
        for (int n = 0; n < 4; ++n)
            b[n] = *(const short8*)&smem[slot + 8192 + (wc * 64 + n * 16 + l16) * 32 + qx];
#pragma unroll
        for (int m = 0; m < 8; ++m)
            a[m] = *(const short8*)&smem[slot + (wr * 128 + m * 16 + l16) * 32 + qx];
        asm volatile("s_waitcnt lgkmcnt(0)" ::: "memory");
        __builtin_amdgcn_sched_barrier(0);
        __builtin_amdgcn_s_setprio(1);
#pragma unroll
        for (int m = 0; m < 8; ++m)
#pragma unroll
            for (int n = 0; n < 4; ++n)
                acc[m][n] = __builtin_amdgcn_mfma_f32_16x16x32_bf16(a[m], b[n], acc[m][n], 0, 0, 0);
        __builtin_amdgcn_s_setprio(0);
    };

    // prologue: stage tiles 0,1,2 (12 loads in flight)
    stage(0); stage(1); stage(2);

    // main loop: vmcnt(8) => tile t landed (tiles t+1,t+2 = 8 loads stay in
    // flight). barrier proves all waves finished reading tile t-1, so
    // stage(t+3) may safely reuse slot (t-1)&3.
#pragma unroll 1
    for (int t = 0; t < 14; ++t) {
        asm volatile("s_waitcnt vmcnt(8)" ::: "memory");
        __builtin_amdgcn_s_barrier();
        if (t + 3 < 16) stage(t + 3);
        compute(t);
    }
    asm volatile("s_waitcnt vmcnt(4)" ::: "memory");
    __builtin_amdgcn_s_barrier();
    compute(14);
    asm volatile("s_waitcnt vmcnt(0)" ::: "memory");
    __builtin_amdgcn_s_barrier();
    compute(15);

    __syncthreads();

    // ---- epilogue: two 128-row halves via padded [128][264] LDS stage ----
#pragma unroll 1
    for (int h = 0; h < 2; ++h) {
        if (wr == h) {
#pragma unroll
            for (int n = 0; n < 4; ++n) {
                const int col = wc * 64 + n * 16 + l16;
                const float bv = bias[n0 + col];
#pragma unroll
                for (int m = 0; m < 8; ++m)
#pragma unroll
                    for (int r = 0; r < 4; ++r)
                        smem[(m * 16 + quad * 4 + r) * 264 + col] = f2bf(acc[m][n][r] + bv);
            }
        }
        __syncthreads();
        if (n0 < 1024) {
            // Q or K planes: [bh][49][32]; 16B chunks, 64B-line aligned.
            const int c   = n0 >> 9;
            const int hh0 = (n0 & 511) >> 5;
            u16* base = qkvp + (size_t)c * QTOT;
#pragma unroll
            for (int it = 0; it < 8; ++it) {
                const int idx  = it * 512 + tid;      // 0..4095
                const int row  = idx >> 5;            // 0..127
                const int hb   = (idx >> 2) & 7;      // 8 head-blocks of 32 cols
                const int part = idx & 3;
                short8 v = *(const short8*)&smem[row * 264 + hb * 32 + part * 8];
                const int rg = m0 + h * 128 + row;
                const int b2 = (int)((unsigned)rg / 49u);
                const int s  = rg - b2 * 49;
                *(short8*)(base + (size_t)(b2 * 16 + hh0 + hb) * 1568 + s * 32 + part * 8) = v;
            }
        } else {
            // V^T planes: [bh][32 d][64 s]; lanes along s (contiguous dst runs).
            const int hh0 = (n0 - 1024) >> 5;
            u16* base = qkvp + VOFF;
#pragma unroll 8
            for (int it = 0; it < 64; ++it) {
                const int idx = it * 512 + tid;       // 0..32767
                const int col = idx >> 7;             // 0..255 (head*32+d)
                const int row = idx & 127;
                const u16 v = smem[row * 264 + col];
                const int rg = m0 + h * 128 + row;
                const int b2 = (int)((unsigned)rg / 49u);
                const int s  = rg - b2 * 49;
                const int hh = hh0 + (col >> 5);
                const int d  = col & 31;
                base[(size_t)(b2 * 16 + hh) * 2048 + d * 64 + s] = v;
            }
        }
        __syncthreads();
    }
}

// ---------- GEMM: C[M][N] = A[M][K](bf16) * Bt[N][K]^T + bias (f32 out) ----------
// Same 256^2 / BK=32 / ring-4 pipeline; direct coalesced f32 epilogue.
__global__ __launch_bounds__(512, 2)
void gemm_bt(const u16* __restrict__ A, const u16* __restrict__ Bt,
             const float* __restrict__ bias, float* __restrict__ Cout,
             int M, int N, int K) {
    const int tid  = threadIdx.x;
    const int lane = tid & 63, wave = tid >> 6;
    const int quad = lane >> 4, l16 = lane & 15;
    const int wr = wave >> 2, wc = wave & 3;

    // XCD-bijective swizzle: 784 blocks = 8 * 98.
    const int flat = blockIdx.y * 2 + blockIdx.x;
    const int swz  = (flat & 7) * 98 + (flat >> 3);
    const int bx = swz & 1;
    const int by = swz >> 1;
    const int m0 = by * 256, n0 = bx * 256;

    __shared__ u16 smem[65536];

    const u16* Ab = A  + (size_t)m0 * K;
    const u16* Bb = Bt + (size_t)n0 * K;

    const int st_row = tid >> 2;
    const int st_chk = (((tid & 3) ^ ((tid >> 3) & 3))) * 8;
    auto stage = [&](int t) {
        const int slot = (t & 3) * 16384;
        const u16* as_ = Ab + (size_t)st_row * K + t * 32 + st_chk;
        const u16* bs_ = Bb + (size_t)st_row * K + t * 32 + st_chk;
        async_ld16(as_,                    &smem[slot + tid * 8]);
        async_ld16(as_ + (size_t)128 * K,  &smem[slot + 4096 + tid * 8]);
        async_ld16(bs_,                    &smem[slot + 8192 + tid * 8]);
        async_ld16(bs_ + (size_t)128 * K,  &smem[slot + 8192 + 4096 + tid * 8]);
    };

    floatx4 acc[8][4] = {};
    const int qx = (quad ^ ((l16 >> 1) & 3)) * 8;

    auto compute = [&](int t) {
        const int slot = (t & 3) * 16384;
        short8 a[8], b[4];
#pragma unroll
        for (int n = 0; n < 4; ++n)
            b[n] = *(const short8*)&smem[slot + 8192 + (wc * 64 + n * 16 + l16) * 32 + qx];
#pragma unroll
        for (int m = 0; m < 8; ++m)
            a[m] = *(const short8*)&smem[slot + (wr * 128 + m * 16 + l16) * 32 + qx];
        asm volatile("s_waitcnt lgkmcnt(0)" ::: "memory");
        __builtin_amdgcn_sched_barrier(0);
        __builtin_amdgcn_s_setprio(1);
#pragma unroll
        for (int m = 0; m < 8; ++m)
#pragma unroll
            for (int n = 0; n < 4; ++n)
                acc[m][n] = __builtin_amdgcn_mfma_f32_16x16x32_bf16(a[m], b[n], acc[m][n], 0, 0, 0);
        __builtin_amdgcn_s_setprio(0);
    };

    stage(0); stage(1); stage(2);

#pragma unroll 1
    for (int t = 0; t < 14; ++t) {
        asm volatile("s_waitcnt vmcnt(8)" ::: "memory");
        __builtin_amdgcn_s_barrier();
        if (t + 3 < 16) stage(t + 3);
        compute(t);
    }
    asm volatile("s_waitcnt vmcnt(4)" ::: "memory");
    __builtin_amdgcn_s_barrier();
    compute(14);
    asm volatile("s_waitcnt vmcnt(0)" ::: "memory");
    __builtin_amdgcn_s_barrier();
    compute(15);

    // direct coalesced f32 epilogue (quad-rows of 64B per store group)
#pragma unroll
    for (int n = 0; n < 4; ++n) {
        const int col = n0 + wc * 64 + n * 16 + l16;
        const float bv = bias[col];
#pragma unroll
        for (int m = 0; m < 8; ++m) {
            const int row = m0 + wr * 128 + m * 16 + quad * 4;
#pragma unroll
            for (int r = 0; r < 4; ++r)
                Cout[(size_t)(row + r) * N + col] = acc[m][n][r] + bv;
        }
    }
}

// ---------- attention: one wave per (b,h); direct global frags + register softmax ----------
__global__ __launch_bounds__(64, 4)
void attn2(const u16* __restrict__ qkvp, const float* __restrict__ cmb,
           u16* __restrict__ out) {
    const int bid = blockIdx.x;
    const int b = bid >> 4, h = bid & 15;
    const int lane = threadIdx.x;
    const int quad = lane >> 4, l16 = lane & 15;

    const u16* qb = qkvp + (size_t)(b * 16 + h) * 1568;
    const u16* kb = qb + QTOT;
    const u16* vb = qkvp + VOFF + (size_t)(b * 16 + h) * 2048;   // V^T [32][64]

    __shared__ u16 ps[64 * 72];        // probs, row stride 72 elems (144 B)

    short8 af[4], bfr[4];
#pragma unroll
    for (int i = 0; i < 4; ++i) {
        int r = i * 16 + l16; if (r > 48) r = 48;     // clamp pad rows (outputs discarded)
        af[i] = *(const short8*)(qb + r * 32 + quad * 8);
    }
#pragma unroll
    for (int j = 0; j < 4; ++j) {
        int n = j * 16 + l16; if (n > 48) n = 48;     // clamp pad cols (logits masked)
        bfr[j] = *(const short8*)(kb + n * 32 + quad * 8);
    }

    const float scale = 0.1767766952966369f;          // 32^-0.5
    const float* cb = cmb + (size_t)((b & 63) * 16 + h) * 2401;

#pragma unroll
    for (int i = 0; i < 4; ++i) {
        floatx4 accS[4] = {};
#pragma unroll
        for (int j = 0; j < 4; ++j)
            accS[j] = __builtin_amdgcn_mfma_f32_16x16x32_bf16(af[i], bfr[j], accS[j], 0, 0, 0);
        const int rbase = i * 16 + quad * 4;
#pragma unroll
        for (int r = 0; r < 4; ++r) {
            int row = rbase + r;
            int rc = row < 48 ? row : 48;             // keep table reads in bounds
            float x[4];
#pragma unroll
            for (int j = 0; j < 4; ++j) {
                int col = j * 16 + l16;
                x[j] = (col < SEQ) ? accS[j][r] * scale + cb[rc * 49 + col] : -3.0e38f;
            }
            float m = fmaxf(fmaxf(x[0], x[1]), fmaxf(x[2], x[3]));
#pragma unroll
            for (int off = 1; off < 16; off <<= 1) m = fmaxf(m, __shfl_xor(m, off));
            float e[4], s = 0.f;
#pragma unroll
            for (int j = 0; j < 4; ++j) { e[j] = __expf(x[j] - m); s += e[j]; }
#pragma unroll
            for (int off = 1; off < 16; off <<= 1) s += __shfl_xor(s, off);
            float inv = __builtin_amdgcn_rcpf(s);
#pragma unroll
            for (int j = 0; j < 4; ++j)
                ps[row * 72 + j * 16 + l16] = f2bf(e[j] * inv);
        }
    }
    __syncthreads();

    // PV: O[64x32] = P[64x64] * V[64x32] via A=ps rows, B=V^T rows
    floatx4 accO[4][2] = {};
#pragma unroll
    for (int kt = 0; kt < 2; ++kt) {
        short8 pf[4], vf[2];
#pragma unroll
        for (int i = 0; i < 4; ++i)
            pf[i] = *(const short8*)&ps[(i * 16 + l16) * 72 + kt * 32 + quad * 8];
#pragma unroll
        for (int jn = 0; jn < 2; ++jn)
            vf[jn] = *(const short8*)(vb + (jn * 16 + l16) * 64 + kt * 32 + quad * 8);
#pragma unroll
        for (int i = 0; i < 4; ++i)
#pragma unroll
            for (int jn = 0; jn < 2; ++jn)
                accO[i][jn] = __builtin_amdgcn_mfma_f32_16x16x32_bf16(pf[i], vf[jn], accO[i][jn], 0, 0, 0);
    }

    u16* op = out + (size_t)b * SEQ * DIM + h * HD;
#pragma unroll
    for (int i = 0; i < 4; ++i)
#pragma unroll
        for (int jn = 0; jn < 2; ++jn)
#pragma unroll
            for (int r = 0; r < 4; ++r) {
                int row = i * 16 + quad * 4 + r;
                if (row < SEQ)
                    op[(size_t)row * DIM + jn * 16 + l16] = f2bf(accO[i][jn][r]);
            }
}

extern "C" void kernel_launch(void* const* d_in, const int* in_sizes, int n_in,
                              void* d_out, int out_size, void* d_ws, size_t ws_size,
                              hipStream_t stream) {
    const float* x         = (const float*)d_in[0];
    const float* mask      = (const float*)d_in[1];
    const float* qkv_w     = (const float*)d_in[2];
    const float* qkv_b     = (const float*)d_in[3];
    const float* proj_w    = (const float*)d_in[4];
    const float* proj_b    = (const float*)d_in[5];
    const float* bias_tab  = (const float*)d_in[6];
    const int*   rel_idx   = (const int*)d_in[7];
    float* out = (float*)d_out;

    char* ws = (char*)d_ws;
    u16*   xbf     = (u16*)(ws + 0);               // reused as attn_out
    u16*   qkvp    = (u16*)(ws + 102760448);
    float* cmb     = (float*)(ws + 442499072);
    u16*   wqkv_t  = (u16*)(ws + 452333568);
    u16*   wproj_t = (u16*)(ws + 453906432);

    // x -> bf16 (51,380,224 elems = 12,845,056 float4s)
    conv_f32_bf16<<<50176, 256, 0, stream>>>(x, xbf, 12845056);
    // weight transposes
    transpose_conv<<<3072, 256, 0, stream>>>(qkv_w, wqkv_t, 1536);
    transpose_conv<<<1024, 256, 0, stream>>>(proj_w, wproj_t, 512);
    // combined bias+mask table
    build_combined<<<9604, 256, 0, stream>>>(mask, bias_tab, rel_idx, cmb);
    // zero V^T pad rows (s in [48,64)) before gemm_qkv rewrites s=48
    zero_vpad<<<4096, 256, 0, stream>>>(qkvp);
    // qkv GEMM -> scattered per-head planes (256^2 ring-4 pipeline)
    gemm_qkv<<<dim3(6, 392), 512, 0, stream>>>(xbf, wqkv_t, qkv_b, qkvp);
    // attention -> attn_out (reuses xbf)
    attn2<<<B_WIN * NHEAD, 64, 0, stream>>>(qkvp, cmb, xbf);
    // out = attn @ proj_w + proj_b
    gemm_bt<<<dim3(2, 392), 512, 0, stream>>>(xbf, wproj_t, proj_b, out,
                                              MROWS, 512, 512);
}

// Round 4
// 856.235 us; speedup vs baseline: 1.0286x; 1.0286x over previous
//
#include <hip/hip_runtime.h>

// WindowAttention (Swin-style) on gfx950 — R7 (R6 bugfix).
// R7 = R6 with build_combined writing a FRAGMENT-ORDERED padded table:
//   within each 64-float row group, position l16*4 + j holds logit column
//   j*16 + l16 (cols >= 49 -> -1e30). attn2's float4 read at l16*4 then
//   matches accS[0..3][r] exactly (R6 had this permuted -> absmax 3.29).
// Other R6 changes retained:
//   * GEMMs: R4 128^2 / 2-block-per-CU structure (R5 ring-4 regressed).
//   * attn2: 2 (b,h) pairs per wave, pipelined loads.
//   * padded cmb table lives in d_out (scratch until gemm_bt overwrites).

typedef unsigned short u16;
typedef __attribute__((ext_vector_type(8))) short short8;
typedef __attribute__((ext_vector_type(4))) float floatx4;

#define B_WIN 2048
#define SEQ 49
#define DIM 512
#define NHEAD 16
#define HD 32
#define MROWS (B_WIN * SEQ)          // 100352
#define QTOT 51380224u               // 2048*16*49*32 elems (one Q or K plane set)
#define VOFF 102760448u              // elem offset of Vt planes ( = 2*QTOT)

__device__ __forceinline__ u16 f2bf(float x) {
    unsigned u = __float_as_uint(x);
    u += 0x7fffu + ((u >> 16) & 1u);   // RNE
    return (u16)(u >> 16);
}

__device__ __forceinline__ void async_ld16(const void* g, void* l) {
    __builtin_amdgcn_global_load_lds(
        (const __attribute__((address_space(1))) void*)g,
        (__attribute__((address_space(3))) void*)l, 16, 0, 0);
}

// ---------- conversion kernels ----------
__global__ void conv_f32_bf16(const float* __restrict__ in, u16* __restrict__ out, int n4) {
    int id = blockIdx.x * 256 + threadIdx.x;
    if (id >= n4) return;
    float4 v = ((const float4*)in)[id];
    uint2 o;
    o.x = (unsigned)f2bf(v.x) | ((unsigned)f2bf(v.y) << 16);
    o.y = (unsigned)f2bf(v.z) | ((unsigned)f2bf(v.w) << 16);
    *(uint2*)(out + (size_t)id * 4) = o;
}

// in: [512][Cn] f32 (k-major). out: [Cn][512] bf16 (n-major).
__global__ void transpose_conv(const float* __restrict__ in, u16* __restrict__ out, int Cn) {
    int id = blockIdx.x * 256 + threadIdx.x;
    if (id >= Cn * 512) return;
    int k = id & 511;
    int n = id >> 9;
    out[id] = f2bf(in[(size_t)k * Cn + n]);
}

// Fragment-ordered padded combined table: for each (w,h,row), 64 floats where
// slot l16*4 + j holds logit column c = j*16 + l16:
//   c < 49 : bias_table[rel_idx[row*49+c]][h] + mask[w][row*49+c]
//   c >= 49: -1e30 (softmax pad)
// attn2 reads float4 at slot l16*4 -> {c = l16, 16+l16, 32+l16, 48+l16},
// matching the 16x16 MFMA C-fragment columns of accS[0..3].
__global__ void build_combined(const float* __restrict__ mask, const float* __restrict__ bias_table,
                               const int* __restrict__ rel_idx, float* __restrict__ cmb) {
    int id = blockIdx.x * 256 + threadIdx.x;    // 64*16*49*64 = 3,211,264
    if (id >= 64 * 16 * 49 * 64) return;
    int w64 = id & 63;
    int j   = w64 & 3;          // fragment block index
    int l   = w64 >> 2;         // lane l16
    int c   = j * 16 + l;       // logit column
    int t   = id >> 6;
    int row = t % 49;
    int wh  = t / 49;
    int h = wh & 15, w = wh >> 4;
    float v = -1.0e30f;
    if (c < 49) {
        int ij = row * 49 + c;
        v = bias_table[rel_idx[ij] * NHEAD + h] + mask[(size_t)w * 2401 + ij];
    }
    cmb[id] = v;
}

// zero V^T pad region: elems s in [48,64) per (bh, d). gemm_qkv later rewrites s=48.
__global__ void zero_vpad(u16* __restrict__ qkvp) {
    int id = blockIdx.x * 256 + threadIdx.x;     // 2048*16*32 = 1,048,576
    if (id >= 2048 * 16 * 32) return;
    uint4 z = {0u, 0u, 0u, 0u};
    u16* p = qkvp + VOFF + (size_t)id * 64 + 48; // byte offset 96: 16B aligned
    *(uint4*)p = z;                               // elems 48..55
    *((uint4*)p + 1) = z;                         // elems 56..63
}

// ---------- GEMM1: qkv = x @ qkv_w + b, scattered to per-head planes ----------
__global__ __launch_bounds__(256, 2)
void gemm_qkv(const u16* __restrict__ A, const u16* __restrict__ Bt,
              const float* __restrict__ bias, u16* __restrict__ qkvp) {
    const int K = 512;
    const int tid  = threadIdx.x;
    const int lane = tid & 63, wave = tid >> 6;
    const int quad = lane >> 4, l16 = lane & 15;
    const int wr = wave >> 1, wc = wave & 1;

    // XCD-bijective swizzle: 9408 blocks = 8 * 1176.
    const int flat = blockIdx.y * 12 + blockIdx.x;
    const int swz  = (flat & 7) * 1176 + (flat >> 3);
    const int bx = swz % 12;
    const int by = swz / 12;
    const int m0 = by * 128, n0 = bx * 128;

    // K-loop: As = smem[0..4095], Bs = smem[4096..8191] (each 128x32 u16).
    // Epilogue: whole buffer reused as 128x136 bf16 stage.
    __shared__ u16 smem[128 * 136];
    u16* As = smem;
    u16* Bs = smem + 4096;

    const int f0 = (wave * 2 + 0) * 512 + lane * 8;
    const int f1 = (wave * 2 + 1) * 512 + lane * 8;
    const int r0 = f0 >> 5, c0 = f0 & 31;
    const int r1 = f1 >> 5, c1 = f1 & 31;
    const u16* Ab = A + (size_t)m0 * K;
    const u16* Bb = Bt + (size_t)n0 * K;

    floatx4 acc[4][4] = {};

    for (int kt = 0; kt < K; kt += 32) {
        async_ld16(Ab + (size_t)r0 * K + kt + c0, &As[f0]);
        async_ld16(Ab + (size_t)r1 * K + kt + c1, &As[f1]);
        async_ld16(Bb + (size_t)r0 * K + kt + c0, &Bs[f0]);
        async_ld16(Bb + (size_t)r1 * K + kt + c1, &Bs[f1]);
        __syncthreads();
        short8 af[4], bf[4];
#pragma unroll
        for (int i = 0; i < 4; ++i)
            af[i] = *(const short8*)&As[(wr * 64 + i * 16 + l16) * 32 + quad * 8];
#pragma unroll
        for (int j = 0; j < 4; ++j)
            bf[j] = *(const short8*)&Bs[(wc * 64 + j * 16 + l16) * 32 + quad * 8];
#pragma unroll
        for (int i = 0; i < 4; ++i)
#pragma unroll
            for (int j = 0; j < 4; ++j)
                acc[i][j] = __builtin_amdgcn_mfma_f32_16x16x32_bf16(af[i], bf[j], acc[i][j], 0, 0, 0);
        __syncthreads();
    }

    // ---- epilogue phase A: acc (+bias) -> bf16 into padded LDS stage ----
#pragma unroll
    for (int j = 0; j < 4; ++j) {
        const int col = wc * 64 + j * 16 + l16;
        const float bv = bias[n0 + col];
#pragma unroll
        for (int i = 0; i < 4; ++i)
#pragma unroll
            for (int r = 0; r < 4; ++r) {
                const int row = wr * 64 + i * 16 + quad * 4 + r;
                smem[row * 136 + col] = f2bf(acc[i][j][r] + bv);
            }
    }
    __syncthreads();

    // ---- epilogue phase B: cooperative coalesced writeout ----
    if (n0 < 1024) {
        // Q or K planes: [bh][49][32]; 16B chunks, 64B-line aligned.
        const int c   = n0 >> 9;
        const int hh0 = (n0 & 511) >> 5;
        u16* base = qkvp + (size_t)c * QTOT;
#pragma unroll
        for (int it = 0; it < 8; ++it) {
            const int idx  = it * 256 + tid;      // 0..2047
            const int row  = idx >> 4;
            const int hb   = (idx >> 2) & 3;
            const int part = idx & 3;
            short8 v = *(const short8*)&smem[row * 136 + hb * 32 + part * 8];
            const int rg = m0 + row;
            const int b2 = (int)((unsigned)rg / 49u);
            const int s  = rg - b2 * 49;
            *(short8*)(base + (size_t)(b2 * 16 + hh0 + hb) * 1568 + s * 32 + part * 8) = v;
        }
    } else {
        // V^T planes: [bh][32 d][64 s]; lanes along s (contiguous dst runs).
        const int hh0 = (n0 - 1024) >> 5;
        u16* base = qkvp + VOFF;
#pragma unroll 16
        for (int it = 0; it < 64; ++it) {
            const int idx = it * 256 + tid;       // 0..16383
            const int col = idx >> 7;             // 0..127 (tile col = head*32+d)
            const int row = idx & 127;
            const u16 v = smem[row * 136 + col];
            const int rg = m0 + row;
            const int b2 = (int)((unsigned)rg / 49u);
            const int s  = rg - b2 * 49;
            const int hh = hh0 + (col >> 5);
            const int d  = col & 31;
            base[(size_t)(b2 * 16 + hh) * 2048 + d * 64 + s] = v;
        }
    }
}

// ---------- GEMM: C[M][N] = A[M][K](bf16) * Bt[N][K]^T + bias (f32 out) ----------
__global__ __launch_bounds__(256, 2)
void gemm_bt(const u16* __restrict__ A, const u16* __restrict__ Bt,
             const float* __restrict__ bias, float* __restrict__ Cout,
             int M, int N, int K) {
    const int tid  = threadIdx.x;
    const int lane = tid & 63, wave = tid >> 6;
    const int quad = lane >> 4, l16 = lane & 15;
    const int wr = wave >> 1, wc = wave & 1;

    // XCD-bijective swizzle (applied when grid divides by 8).
    const int nbx = gridDim.x, nby = gridDim.y;
    const int total = nbx * nby;
    const int flat = blockIdx.y * nbx + blockIdx.x;
    const int swz = ((total & 7) == 0) ? ((flat & 7) * (total >> 3) + (flat >> 3)) : flat;
    const int bx = swz % nbx;
    const int by = swz / nbx;
    const int m0 = by * 128, n0 = bx * 128;

    __shared__ u16 As[128 * 32];
    __shared__ u16 Bs[128 * 32];

    const int f0 = (wave * 2 + 0) * 512 + lane * 8;
    const int f1 = (wave * 2 + 1) * 512 + lane * 8;
    const int r0 = f0 >> 5, c0 = f0 & 31;
    const int r1 = f1 >> 5, c1 = f1 & 31;
    const u16* Ab = A + (size_t)m0 * K;
    const u16* Bb = Bt + (size_t)n0 * K;

    floatx4 acc[4][4] = {};

    for (int kt = 0; kt < K; kt += 32) {
        async_ld16(Ab + (size_t)r0 * K + kt + c0, &As[f0]);
        async_ld16(Ab + (size_t)r1 * K + kt + c1, &As[f1]);
        async_ld16(Bb + (size_t)r0 * K + kt + c0, &Bs[f0]);
        async_ld16(Bb + (size_t)r1 * K + kt + c1, &Bs[f1]);
        __syncthreads();
        short8 af[4], bf[4];
#pragma unroll
        for (int i = 0; i < 4; ++i)
            af[i] = *(const short8*)&As[(wr * 64 + i * 16 + l16) * 32 + quad * 8];
#pragma unroll
        for (int j = 0; j < 4; ++j)
            bf[j] = *(const short8*)&Bs[(wc * 64 + j * 16 + l16) * 32 + quad * 8];
#pragma unroll
        for (int i = 0; i < 4; ++i)
#pragma unroll
            for (int j = 0; j < 4; ++j)
                acc[i][j] = __builtin_amdgcn_mfma_f32_16x16x32_bf16(af[i], bf[j], acc[i][j], 0, 0, 0);
        __syncthreads();
    }

#pragma unroll
    for (int i = 0; i < 4; ++i) {
#pragma unroll
        for (int j = 0; j < 4; ++j) {
            int col = n0 + wc * 64 + j * 16 + l16;
            float bv = bias[col];
#pragma unroll
            for (int r = 0; r < 4; ++r) {
                int row = m0 + wr * 64 + i * 16 + quad * 4 + r;
                Cout[(size_t)row * N + col] = acc[i][j][r] + bv;
            }
        }
    }
}

// ---------- attention: one wave per 2 (b,h) pairs; pipelined; register softmax ----------
__global__ __launch_bounds__(64, 4)
void attn2(const u16* __restrict__ qkvp, const float* __restrict__ cmbp,
           u16* __restrict__ out) {
    const int lane = threadIdx.x;
    const int quad = lane >> 4, l16 = lane & 15;
    const int p0 = blockIdx.x * 2;                 // pairs p0, p0+1 (same b)
    const int b  = p0 >> 4, h0 = p0 & 15;

    const u16* qb0 = qkvp + (size_t)p0 * 1568;
    const u16* kb0 = qb0 + QTOT;
    const u16* qb1 = qb0 + 1568;
    const u16* kb1 = kb0 + 1568;
    const u16* vb0 = qkvp + VOFF + (size_t)p0 * 2048;   // V^T [32][64]
    const u16* vb1 = vb0 + 2048;

    const float* cb0 = cmbp + (size_t)(((b & 63) * 16 + h0) * 49) * 64;
    const float* cb1 = cb0 + 49 * 64;

    u16* op0 = out + (size_t)b * SEQ * DIM + h0 * HD;
    u16* op1 = op0 + HD;

    __shared__ u16 ps[64 * 72];        // probs, row stride 72 elems (144 B)

    int rr[4];
#pragma unroll
    for (int i = 0; i < 4; ++i) { int r = i * 16 + l16; rr[i] = r > 48 ? 48 : r; }

    // issue Q/K for both pairs up front — pair-1 latency hides under pair-0 work
    short8 af0[4], bf0[4], af1[4], bf1[4];
#pragma unroll
    for (int i = 0; i < 4; ++i) af0[i] = *(const short8*)(qb0 + rr[i] * 32 + quad * 8);
#pragma unroll
    for (int j = 0; j < 4; ++j) bf0[j] = *(const short8*)(kb0 + rr[j] * 32 + quad * 8);
#pragma unroll
    for (int i = 0; i < 4; ++i) af1[i] = *(const short8*)(qb1 + rr[i] * 32 + quad * 8);
#pragma unroll
    for (int j = 0; j < 4; ++j) bf1[j] = *(const short8*)(kb1 + rr[j] * 32 + quad * 8);

    const float scale = 0.1767766952966369f;      // 32^-0.5

    auto do_pair = [&](const short8* af, const short8* bfr, const float* cb,
                       const u16* vb, u16* op) {
        // V loads issued first: latency hides under QK^T + softmax
        short8 vf[2][2];
#pragma unroll
        for (int kt = 0; kt < 2; ++kt)
#pragma unroll
            for (int jn = 0; jn < 2; ++jn)
                vf[kt][jn] = *(const short8*)(vb + (jn * 16 + l16) * 64 + kt * 32 + quad * 8);

#pragma unroll
        for (int i = 0; i < 4; ++i) {
            floatx4 accS[4] = {};
#pragma unroll
            for (int j = 0; j < 4; ++j)
                accS[j] = __builtin_amdgcn_mfma_f32_16x16x32_bf16(af[i], bfr[j], accS[j], 0, 0, 0);
            const int rbase = i * 16 + quad * 4;
#pragma unroll
            for (int r = 0; r < 4; ++r) {
                const int row = rbase + r;
                const int rc = row < 48 ? row : 48;
                // fragment-ordered table: float4 at l16*4 = cols {l16,16+l16,32+l16,48+l16}
                float4 c4 = *(const float4*)(cb + rc * 64 + l16 * 4);
                float x[4] = { accS[0][r] * scale + c4.x, accS[1][r] * scale + c4.y,
                               accS[2][r] * scale + c4.z, accS[3][r] * scale + c4.w };
                float m = fmaxf(fmaxf(x[0], x[1]), fmaxf(x[2], x[3]));
#pragma unroll
                for (int off = 1; off < 16; off <<= 1) m = fmaxf(m, __shfl_xor(m, off));
                float e[4], s = 0.f;
#pragma unroll
                for (int j = 0; j < 4; ++j) { e[j] = __expf(x[j] - m); s += e[j]; }
#pragma unroll
                for (int off = 1; off < 16; off <<= 1) s += __shfl_xor(s, off);
                float inv = __builtin_amdgcn_rcpf(s);
#pragma unroll
                for (int j = 0; j < 4; ++j)
                    ps[row * 72 + j * 16 + l16] = f2bf(e[j] * inv);
            }
        }
        __syncthreads();   // single wave: cheap; orders ds_write -> ds_read

        // PV: O[64x32] = P[64x64] * V[64x32] via A=ps rows, B=V^T rows
        floatx4 accO[4][2] = {};
#pragma unroll
        for (int kt = 0; kt < 2; ++kt) {
            short8 pf[4];
#pragma unroll
            for (int i = 0; i < 4; ++i)
                pf[i] = *(const short8*)&ps[(i * 16 + l16) * 72 + kt * 32 + quad * 8];
#pragma unroll
            for (int i = 0; i < 4; ++i)
#pragma unroll
                for (int jn = 0; jn < 2; ++jn)
                    accO[i][jn] = __builtin_amdgcn_mfma_f32_16x16x32_bf16(pf[i], vf[kt][jn], accO[i][jn], 0, 0, 0);
        }
        __syncthreads();   // protect ps reuse by next pair

#pragma unroll
        for (int i = 0; i < 4; ++i)
#pragma unroll
            for (int jn = 0; jn < 2; ++jn)
#pragma unroll
                for (int r = 0; r < 4; ++r) {
                    int row = i * 16 + quad * 4 + r;
                    if (row < SEQ)
                        op[(size_t)row * DIM + jn * 16 + l16] = f2bf(accO[i][jn][r]);
                }
    };

    do_pair(af0, bf0, cb0, vb0, op0);
    do_pair(af1, bf1, cb1, vb1, op1);
}

extern "C" void kernel_launch(void* const* d_in, const int* in_sizes, int n_in,
                              void* d_out, int out_size, void* d_ws, size_t ws_size,
                              hipStream_t stream) {
    const float* x         = (const float*)d_in[0];
    const float* mask      = (const float*)d_in[1];
    const float* qkv_w     = (const float*)d_in[2];
    const float* qkv_b     = (const float*)d_in[3];
    const float* proj_w    = (const float*)d_in[4];
    const float* proj_b    = (const float*)d_in[5];
    const float* bias_tab  = (const float*)d_in[6];
    const int*   rel_idx   = (const int*)d_in[7];
    float* out = (float*)d_out;

    char* ws = (char*)d_ws;
    u16*   xbf     = (u16*)(ws + 0);               // reused as attn_out
    u16*   qkvp    = (u16*)(ws + 102760448);
    u16*   wqkv_t  = (u16*)(ws + 452333568);
    u16*   wproj_t = (u16*)(ws + 453906432);
    // fragment-ordered padded combined table lives in d_out (scratch until gemm_bt):
    float* cmb     = out;                          // 64*16*49*64 f32 = 12.8 MB

    // x -> bf16 (51,380,224 elems = 12,845,056 float4s)
    conv_f32_bf16<<<50176, 256, 0, stream>>>(x, xbf, 12845056);
    // weight transposes
    transpose_conv<<<3072, 256, 0, stream>>>(qkv_w, wqkv_t, 1536);
    transpose_conv<<<1024, 256, 0, stream>>>(proj_w, wproj_t, 512);
    // fragment-ordered padded combined bias+mask table -> d_out scratch
    build_combined<<<12544, 256, 0, stream>>>(mask, bias_tab, rel_idx, cmb);
    // zero V^T pad rows (s in [48,64)) before gemm_qkv rewrites s=48
    zero_vpad<<<4096, 256, 0, stream>>>(qkvp);
    // qkv GEMM -> scattered per-head planes (LDS-staged coalesced epilogue)
    gemm_qkv<<<dim3(12, 784), 256, 0, stream>>>(xbf, wqkv_t, qkv_b, qkvp);
    // attention (2 pairs per wave) -> attn_out (reuses xbf)
    attn2<<<B_WIN * NHEAD / 2, 64, 0, stream>>>(qkvp, cmb, xbf);
    // out = attn @ proj_w + proj_b (overwrites the cmb scratch)
    gemm_bt<<<dim3(4, 784), 256, 0, stream>>>(xbf, wproj_t, proj_b, out,
                                              MROWS, 512, 512);
}